// Round 1
// baseline (1459.052 us; speedup 1.0000x reference)
//
#include <hip/hip_runtime.h>
#include <math.h>

#define NN 50000
#define NE 600000
#define DIM 128
#define NL 12
#define BM 128
#define BK 32

// ---------------- CSR build ----------------
__global__ void count_kernel(const int* __restrict__ dst, int* __restrict__ counts) {
    int e = blockIdx.x * blockDim.x + threadIdx.x;
    if (e < NE) atomicAdd(&counts[dst[e]], 1);
}

__global__ void scan_kernel(const int* __restrict__ counts, int* __restrict__ offsets) {
    __shared__ int sm[1024];
    int base = 0;
    if (threadIdx.x == 0) offsets[0] = 0;
    for (int start = 0; start < NN; start += 1024) {
        int i = start + threadIdx.x;
        int v = (i < NN) ? counts[i] : 0;
        sm[threadIdx.x] = v;
        __syncthreads();
        for (int off = 1; off < 1024; off <<= 1) {
            int t = (threadIdx.x >= off) ? sm[threadIdx.x - off] : 0;
            __syncthreads();
            sm[threadIdx.x] += t;
            __syncthreads();
        }
        if (i < NN) offsets[i + 1] = base + sm[threadIdx.x];
        base += sm[1023];   // valid: all adds done (loop ends with sync)
        __syncthreads();    // protect sm before next chunk overwrites
    }
}

__global__ void fill_kernel(const int* __restrict__ src, const int* __restrict__ dst,
                            const int* __restrict__ offsets, int* __restrict__ cursor,
                            int* __restrict__ csr) {
    int e = blockIdx.x * blockDim.x + threadIdx.x;
    if (e < NE) {
        int d = dst[e];
        int p = atomicAdd(&cursor[d], 1);
        csr[offsets[d] + p] = src[e];
    }
}

// ---------------- aggregation: one wave per node ----------------
// AGGR: 0=sum, 1=mean, 2=max
template <int AGGR>
__global__ void aggregate_kernel(const float* __restrict__ h, float* __restrict__ agg,
                                 const int* __restrict__ csr, const int* __restrict__ offsets) {
    int wid = (blockIdx.x * blockDim.x + threadIdx.x) >> 6;
    int lane = threadIdx.x & 63;
    if (wid >= NN) return;
    int s0 = offsets[wid], s1 = offsets[wid + 1];
    float ax, ay;
    if (AGGR == 2) { ax = -INFINITY; ay = -INFINITY; } else { ax = 0.f; ay = 0.f; }
    int e = s0;
    for (; e + 1 < s1; e += 2) {
        int a = csr[e], b = csr[e + 1];
        float2 va = *reinterpret_cast<const float2*>(h + (size_t)a * DIM + lane * 2);
        float2 vb = *reinterpret_cast<const float2*>(h + (size_t)b * DIM + lane * 2);
        if (AGGR == 2) {
            ax = fmaxf(ax, fmaxf(va.x, vb.x));
            ay = fmaxf(ay, fmaxf(va.y, vb.y));
        } else {
            ax += va.x + vb.x;
            ay += va.y + vb.y;
        }
    }
    if (e < s1) {
        int a = csr[e];
        float2 va = *reinterpret_cast<const float2*>(h + (size_t)a * DIM + lane * 2);
        if (AGGR == 2) { ax = fmaxf(ax, va.x); ay = fmaxf(ay, va.y); }
        else           { ax += va.x;          ay += va.y; }
    }
    int deg = s1 - s0;
    if (AGGR == 1) { float inv = 1.f / (float)(deg > 0 ? deg : 1); ax *= inv; ay *= inv; }
    if (AGGR == 2 && deg == 0) { ax = 0.f; ay = 0.f; }
    float2 r; r.x = ax; r.y = ay;
    *reinterpret_cast<float2*>(agg + (size_t)wid * DIM + lane * 2) = r;
}

// ---------------- fused dual GEMM: C = relu(A1@Wa^T [+ A2@Wb^T] + bias) ----------------
// W is row-major [128 out][128 k]. In-place C==A1 is safe (block reads its own rows
// fully before the epilogue writes them; no cross-block row sharing).
__global__ __launch_bounds__(256) void gemm_kernel(
    const float* __restrict__ A1, const float* __restrict__ Wa,
    const float* __restrict__ A2, const float* __restrict__ Wb,
    const float* __restrict__ bias, float* __restrict__ C) {
    __shared__ float As[BK][BM + 4];    // k-major, pad -> 2-way max on reads
    __shared__ float Ws[BK][DIM + 4];
    int t = threadIdx.x;
    int tx = t & 15;    // col group: cols {4tx..4tx+3} and {64+4tx..64+4tx+3}
    int ty = t >> 4;    // row group: rows 8ty..8ty+7
    int row0 = blockIdx.x * BM;
    float acc[8][8];
#pragma unroll
    for (int r = 0; r < 8; ++r)
#pragma unroll
        for (int c = 0; c < 8; ++c) acc[r][c] = 0.f;

    for (int pass = 0; pass < 2; ++pass) {
        const float* A = pass ? A2 : A1;
        const float* W = pass ? Wb : Wa;
        if (!A) break;
        for (int kt = 0; kt < DIM; kt += BK) {
#pragma unroll
            for (int i = 0; i < 4; ++i) {
                int l = t + i * 256;
                int row = l >> 3;          // 0..127
                int kq = (l & 7) << 2;     // 0,4,...,28
                int grow = row0 + row;
                float4 v = (grow < NN)
                    ? *reinterpret_cast<const float4*>(A + (size_t)grow * DIM + kt + kq)
                    : make_float4(0.f, 0.f, 0.f, 0.f);
                As[kq + 0][row] = v.x; As[kq + 1][row] = v.y;
                As[kq + 2][row] = v.z; As[kq + 3][row] = v.w;
                float4 w = *reinterpret_cast<const float4*>(W + (size_t)row * DIM + kt + kq);
                Ws[kq + 0][row] = w.x; Ws[kq + 1][row] = w.y;
                Ws[kq + 2][row] = w.z; Ws[kq + 3][row] = w.w;
            }
            __syncthreads();
#pragma unroll
            for (int kk = 0; kk < BK; ++kk) {
                float4 a0 = *reinterpret_cast<const float4*>(&As[kk][ty * 8]);
                float4 a1 = *reinterpret_cast<const float4*>(&As[kk][ty * 8 + 4]);
                float4 w0 = *reinterpret_cast<const float4*>(&Ws[kk][tx * 4]);
                float4 w1 = *reinterpret_cast<const float4*>(&Ws[kk][tx * 4 + 64]);
                float av[8] = {a0.x, a0.y, a0.z, a0.w, a1.x, a1.y, a1.z, a1.w};
                float wv[8] = {w0.x, w0.y, w0.z, w0.w, w1.x, w1.y, w1.z, w1.w};
#pragma unroll
                for (int r = 0; r < 8; ++r)
#pragma unroll
                    for (int c = 0; c < 8; ++c)
                        acc[r][c] = fmaf(av[r], wv[c], acc[r][c]);
            }
            __syncthreads();
        }
    }
    float4 b0 = *reinterpret_cast<const float4*>(bias + tx * 4);
    float4 b1v = *reinterpret_cast<const float4*>(bias + tx * 4 + 64);
#pragma unroll
    for (int r = 0; r < 8; ++r) {
        int grow = row0 + ty * 8 + r;
        if (grow < NN) {
            float4 o0, o1;
            o0.x = fmaxf(acc[r][0] + b0.x, 0.f);
            o0.y = fmaxf(acc[r][1] + b0.y, 0.f);
            o0.z = fmaxf(acc[r][2] + b0.z, 0.f);
            o0.w = fmaxf(acc[r][3] + b0.w, 0.f);
            o1.x = fmaxf(acc[r][4] + b1v.x, 0.f);
            o1.y = fmaxf(acc[r][5] + b1v.y, 0.f);
            o1.z = fmaxf(acc[r][6] + b1v.z, 0.f);
            o1.w = fmaxf(acc[r][7] + b1v.w, 0.f);
            *reinterpret_cast<float4*>(C + (size_t)grow * DIM + tx * 4) = o0;
            *reinterpret_cast<float4*>(C + (size_t)grow * DIM + tx * 4 + 64) = o1;
        }
    }
}

// ---------------- final 128 -> 2 projection (no relu) ----------------
__global__ void out_kernel(const float* __restrict__ h2, const float* __restrict__ W2,
                           const float* __restrict__ b2, float* __restrict__ out) {
    int wid = (blockIdx.x * blockDim.x + threadIdx.x) >> 6;
    int lane = threadIdx.x & 63;
    if (wid >= NN) return;
    float2 v  = *reinterpret_cast<const float2*>(h2 + (size_t)wid * DIM + lane * 2);
    float2 w0 = *reinterpret_cast<const float2*>(W2 + lane * 2);
    float2 w1 = *reinterpret_cast<const float2*>(W2 + DIM + lane * 2);
    float s0 = v.x * w0.x + v.y * w0.y;
    float s1 = v.x * w1.x + v.y * w1.y;
    for (int off = 32; off; off >>= 1) {
        s0 += __shfl_down(s0, off);
        s1 += __shfl_down(s1, off);
    }
    if (lane == 0) {
        out[wid * 2 + 0] = s0 + b2[0];
        out[wid * 2 + 1] = s1 + b2[1];
    }
}

extern "C" void kernel_launch(void* const* d_in, const int* in_sizes, int n_in,
                              void* d_out, int out_size, void* d_ws, size_t ws_size,
                              hipStream_t stream) {
    const float* x  = (const float*)d_in[0];
    const int*   ei = (const int*)d_in[1];
    const float* Wl = (const float*)d_in[2];
    const float* bl = (const float*)d_in[3];
    const float* Wr = (const float*)d_in[4];
    const float* W1 = (const float*)d_in[5];
    const float* b1 = (const float*)d_in[6];
    const float* W2 = (const float*)d_in[7];
    const float* b2 = (const float*)d_in[8];
    float* out = (float*)d_out;

    // workspace layout
    int* counts  = (int*)d_ws;              // N ints (reused as cursor)
    int* offsets = counts + NN;             // N+1 ints
    int* csr     = offsets + NN + 1;        // E ints
    size_t fixed = ((size_t)(NN + NN + 1 + NE) * sizeof(int) + 255) & ~(size_t)255;
    float* bufA = (float*)((char*)d_ws + fixed);     // N*D floats
    float* bufB = bufA + (size_t)NN * DIM;           // N*D floats

    const int* src = ei;
    const int* dst = ei + NE;

    hipMemsetAsync(counts, 0, NN * sizeof(int), stream);
    count_kernel<<<(NE + 255) / 256, 256, 0, stream>>>(dst, counts);
    scan_kernel<<<1, 1024, 0, stream>>>(counts, offsets);
    hipMemsetAsync(counts, 0, NN * sizeof(int), stream);
    fill_kernel<<<(NE + 255) / 256, 256, 0, stream>>>(src, dst, offsets, counts, csr);

    static const int AGGRS[NL] = {0, 1, 2, 0, 1, 2, 0, 1, 2, 0, 2, 1};
    const float* h = x;
    dim3 agrd((NN * 64 + 255) / 256);
    dim3 ggrd((NN + BM - 1) / BM);
    for (int i = 0; i < NL; ++i) {
        float* aggbuf = (i & 1) ? bufB : bufA;
        if (AGGRS[i] == 0)
            aggregate_kernel<0><<<agrd, 256, 0, stream>>>(h, aggbuf, csr, offsets);
        else if (AGGRS[i] == 1)
            aggregate_kernel<1><<<agrd, 256, 0, stream>>>(h, aggbuf, csr, offsets);
        else
            aggregate_kernel<2><<<agrd, 256, 0, stream>>>(h, aggbuf, csr, offsets);
        gemm_kernel<<<ggrd, 256, 0, stream>>>(aggbuf, Wl + (size_t)i * DIM * DIM, h,
                                              Wr + (size_t)i * DIM * DIM,
                                              bl + (size_t)i * DIM, aggbuf);
        h = aggbuf;
    }
    // final MLP: relu(h@W1^T + b1) in-place, then 128->2 projection
    gemm_kernel<<<ggrd, 256, 0, stream>>>(h, W1, nullptr, nullptr, b1, (float*)h);
    out_kernel<<<agrd, 256, 0, stream>>>(h, W2, b2, out);
}

// Round 2
// 917.036 us; speedup vs baseline: 1.5911x; 1.5911x over previous
//
#include <hip/hip_runtime.h>
#include <math.h>

#define NN 50000
#define NE 600000
#define DIM 128
#define NL 12

typedef short bf16x8 __attribute__((ext_vector_type(8)));
typedef float f32x4 __attribute__((ext_vector_type(4)));

__device__ __forceinline__ uint f2b_rne(float f) {
    uint u = __float_as_uint(f);
    return (u + 0x7fffu + ((u >> 16) & 1u)) >> 16;
}

// ---------------- fp32 -> bf16 convert (8 elems/thread) ----------------
__global__ void cvt_kernel(const float* __restrict__ in, ushort* __restrict__ out, int n8) {
    int i = blockIdx.x * blockDim.x + threadIdx.x;
    if (i >= n8) return;
    const float4* p = reinterpret_cast<const float4*>(in);
    float4 v0 = p[i * 2], v1 = p[i * 2 + 1];
    uint4 o;
    o.x = (f2b_rne(v0.y) << 16) | f2b_rne(v0.x);
    o.y = (f2b_rne(v0.w) << 16) | f2b_rne(v0.z);
    o.z = (f2b_rne(v1.y) << 16) | f2b_rne(v1.x);
    o.w = (f2b_rne(v1.w) << 16) | f2b_rne(v1.z);
    reinterpret_cast<uint4*>(out)[i] = o;
}

// ---------------- CSR build ----------------
__global__ void count_kernel(const int* __restrict__ dst, int* __restrict__ counts) {
    int e = blockIdx.x * blockDim.x + threadIdx.x;
    if (e < NE) atomicAdd(&counts[dst[e]], 1);
}

// block scans 1024 counts via wave shfl-scan; writes chunk-local inclusive + block sum
__global__ __launch_bounds__(1024) void scan1_kernel(const int* __restrict__ counts,
                                                     int* __restrict__ offsets,
                                                     int* __restrict__ bsums) {
    int b = blockIdx.x, t = threadIdx.x;
    int i = b * 1024 + t;
    int lane = t & 63, wid = t >> 6;
    int val = (i < NN) ? counts[i] : 0;
#pragma unroll
    for (int o = 1; o < 64; o <<= 1) {
        int n = __shfl_up(val, o);
        if (lane >= o) val += n;
    }
    __shared__ int ws[16];
    if (lane == 63) ws[wid] = val;
    __syncthreads();
    if (wid == 0 && lane < 16) {
        int s = ws[lane];
#pragma unroll
        for (int o = 1; o < 16; o <<= 1) {
            int n = __shfl_up(s, o);
            if (lane >= o) s += n;
        }
        ws[lane] = s;
    }
    __syncthreads();
    if (wid) val += ws[wid - 1];
    if (i < NN) offsets[i + 1] = val;
    if (t == 1023) bsums[b] = val;
}

__global__ void scan2_kernel(const int* __restrict__ bsums, int* __restrict__ bbase, int nb) {
    int lane = threadIdx.x;
    int v = (lane < nb) ? bsums[lane] : 0;
    int val = v;
#pragma unroll
    for (int o = 1; o < 64; o <<= 1) {
        int n = __shfl_up(val, o);
        if (lane >= o) val += n;
    }
    if (lane < nb) bbase[lane] = val - v;   // exclusive
}

__global__ void scan3_kernel(int* __restrict__ offsets, const int* __restrict__ bbase) {
    int i = blockIdx.x * blockDim.x + threadIdx.x;
    if (i == 0) { offsets[0] = 0; return; }
    if (i <= NN) offsets[i] += bbase[(i - 1) >> 10];
}

__global__ void fill_kernel(const int* __restrict__ src, const int* __restrict__ dst,
                            const int* __restrict__ offsets, int* __restrict__ cursor,
                            int* __restrict__ csr) {
    int e = blockIdx.x * blockDim.x + threadIdx.x;
    if (e < NE) {
        int d = dst[e];
        int p = atomicAdd(&cursor[d], 1);
        csr[offsets[d] + p] = src[e];
    }
}

// ---------------- aggregation: one wave per node, bf16 in/out, fp32 accum ----------------
// AGGR: 0=sum, 1=mean, 2=max
template <int AGGR>
__global__ void aggregate_kernel(const ushort* __restrict__ h, ushort* __restrict__ agg,
                                 const int* __restrict__ csr, const int* __restrict__ offsets) {
    int wid = (blockIdx.x * blockDim.x + threadIdx.x) >> 6;
    int lane = threadIdx.x & 63;
    if (wid >= NN) return;
    int s0 = offsets[wid], s1 = offsets[wid + 1];
    const uint* hp = reinterpret_cast<const uint*>(h);   // 2 bf16 per uint, row = 64 uints
    float ax, ay;
    if (AGGR == 2) { ax = -INFINITY; ay = -INFINITY; } else { ax = 0.f; ay = 0.f; }
    int e = s0;
    for (; e + 3 < s1; e += 4) {
        int n0 = csr[e], n1 = csr[e + 1], n2 = csr[e + 2], n3 = csr[e + 3];
        uint u0 = hp[(size_t)n0 * 64 + lane];
        uint u1 = hp[(size_t)n1 * 64 + lane];
        uint u2 = hp[(size_t)n2 * 64 + lane];
        uint u3 = hp[(size_t)n3 * 64 + lane];
        float x0 = __uint_as_float(u0 << 16), y0 = __uint_as_float(u0 & 0xffff0000u);
        float x1 = __uint_as_float(u1 << 16), y1 = __uint_as_float(u1 & 0xffff0000u);
        float x2 = __uint_as_float(u2 << 16), y2 = __uint_as_float(u2 & 0xffff0000u);
        float x3 = __uint_as_float(u3 << 16), y3 = __uint_as_float(u3 & 0xffff0000u);
        if (AGGR == 2) {
            ax = fmaxf(fmaxf(ax, fmaxf(x0, x1)), fmaxf(x2, x3));
            ay = fmaxf(fmaxf(ay, fmaxf(y0, y1)), fmaxf(y2, y3));
        } else {
            ax += (x0 + x1) + (x2 + x3);
            ay += (y0 + y1) + (y2 + y3);
        }
    }
    for (; e < s1; ++e) {
        int n0 = csr[e];
        uint u0 = hp[(size_t)n0 * 64 + lane];
        float x0 = __uint_as_float(u0 << 16), y0 = __uint_as_float(u0 & 0xffff0000u);
        if (AGGR == 2) { ax = fmaxf(ax, x0); ay = fmaxf(ay, y0); }
        else           { ax += x0;           ay += y0; }
    }
    int deg = s1 - s0;
    if (AGGR == 1) { float inv = 1.f / (float)(deg > 0 ? deg : 1); ax *= inv; ay *= inv; }
    if (AGGR == 2 && deg == 0) { ax = 0.f; ay = 0.f; }
    uint o = (f2b_rne(ay) << 16) | f2b_rne(ax);
    reinterpret_cast<uint*>(agg)[(size_t)wid * 64 + lane] = o;
}

// ---------------- MFMA GEMM, no LDS: C = relu(A1@Wa^T [+ A2@Wb^T] + bias), bf16 ----------------
// Block = 4 waves x 32 rows = 128 rows. Each wave spans all 128 cols.
// A-frag (16x16x32): lane l holds A[base + (l&15)][kk*32 + (l>>4)*8 .. +7]  (16B load)
// B-frag:            lane l holds W[16c + (l&15)][kk*32 + (l>>4)*8 .. +7]   (B = W^T)
// C/D:               col = l&15, row = (l>>4)*4 + reg   [m89 verified]
__global__ __launch_bounds__(256, 2) void gemm_kernel(
    const ushort* __restrict__ A1, const ushort* __restrict__ Wa,
    const ushort* __restrict__ A2, const ushort* __restrict__ Wb,
    const float* __restrict__ bias, ushort* __restrict__ C, int npass) {
    int t = threadIdx.x;
    int w = t >> 6, l = t & 63;
    int lr = l & 15;
    int lk = (l >> 4) << 3;           // k sub-offset 0,8,16,24
    int row0 = blockIdx.x * 128 + w * 32;

    f32x4 acc[2][8];
#pragma unroll
    for (int r = 0; r < 2; ++r)
#pragma unroll
        for (int c = 0; c < 8; ++c) acc[r][c] = (f32x4){0.f, 0.f, 0.f, 0.f};

    int r0 = min(row0 + lr, NN - 1);        // clamp: OOB rows read row NN-1, results discarded
    int r1 = min(row0 + 16 + lr, NN - 1);

    for (int pass = 0; pass < npass; ++pass) {
        const ushort* A = pass ? A2 : A1;
        const ushort* W = pass ? Wb : Wa;
#pragma unroll
        for (int kk = 0; kk < 4; ++kk) {
            int k = kk * 32 + lk;
            bf16x8 af0 = *reinterpret_cast<const bf16x8*>(A + (size_t)r0 * DIM + k);
            bf16x8 af1 = *reinterpret_cast<const bf16x8*>(A + (size_t)r1 * DIM + k);
            bf16x8 bf[8];
#pragma unroll
            for (int c = 0; c < 8; ++c)
                bf[c] = *reinterpret_cast<const bf16x8*>(W + (size_t)(c * 16 + lr) * DIM + k);
#pragma unroll
            for (int c = 0; c < 8; ++c) {
                acc[0][c] = __builtin_amdgcn_mfma_f32_16x16x32_bf16(af0, bf[c], acc[0][c], 0, 0, 0);
                acc[1][c] = __builtin_amdgcn_mfma_f32_16x16x32_bf16(af1, bf[c], acc[1][c], 0, 0, 0);
            }
        }
    }
    // epilogue: bias + relu + bf16 store
    int rb = (l >> 4) << 2;
#pragma unroll
    for (int c = 0; c < 8; ++c) {
        int col = c * 16 + lr;
        float b = bias[col];
#pragma unroll
        for (int r = 0; r < 2; ++r) {
#pragma unroll
            for (int i = 0; i < 4; ++i) {
                int row = row0 + r * 16 + rb + i;
                if (row < NN) {
                    float v = fmaxf(acc[r][c][i] + b, 0.f);
                    C[(size_t)row * DIM + col] = (ushort)f2b_rne(v);
                }
            }
        }
    }
}

// ---------------- final 128 -> 2 projection ----------------
__global__ void out_kernel(const ushort* __restrict__ h2, const float* __restrict__ W2,
                           const float* __restrict__ b2, float* __restrict__ out) {
    int wid = (blockIdx.x * blockDim.x + threadIdx.x) >> 6;
    int lane = threadIdx.x & 63;
    if (wid >= NN) return;
    uint u = reinterpret_cast<const uint*>(h2)[(size_t)wid * 64 + lane];
    float vx = __uint_as_float(u << 16), vy = __uint_as_float(u & 0xffff0000u);
    float2 w0 = *reinterpret_cast<const float2*>(W2 + lane * 2);
    float2 w1 = *reinterpret_cast<const float2*>(W2 + DIM + lane * 2);
    float s0 = vx * w0.x + vy * w0.y;
    float s1 = vx * w1.x + vy * w1.y;
    for (int off = 32; off; off >>= 1) {
        s0 += __shfl_down(s0, off);
        s1 += __shfl_down(s1, off);
    }
    if (lane == 0) {
        out[wid * 2 + 0] = s0 + b2[0];
        out[wid * 2 + 1] = s1 + b2[1];
    }
}

extern "C" void kernel_launch(void* const* d_in, const int* in_sizes, int n_in,
                              void* d_out, int out_size, void* d_ws, size_t ws_size,
                              hipStream_t stream) {
    const float* x  = (const float*)d_in[0];
    const int*   ei = (const int*)d_in[1];
    const float* Wl = (const float*)d_in[2];
    const float* bl = (const float*)d_in[3];
    const float* Wr = (const float*)d_in[4];
    const float* W1 = (const float*)d_in[5];
    const float* b1 = (const float*)d_in[6];
    const float* W2 = (const float*)d_in[7];
    const float* b2 = (const float*)d_in[8];
    float* out = (float*)d_out;

    // ---- workspace layout ----
    int* counts  = (int*)d_ws;                      // NN
    int* offsets = counts + NN;                     // NN+1
    int* bsums   = offsets + NN + 1;                // 64
    int* bbase   = bsums + 64;                      // 64
    int* csr     = bbase + 64;                      // NE
    size_t fixed = ((size_t)(NN + NN + 1 + 128 + NE) * sizeof(int) + 255) & ~(size_t)255;
    ushort* xb   = (ushort*)((char*)d_ws + fixed);  // NN*DIM bf16
    ushort* bufA = xb + (size_t)NN * DIM;
    ushort* bufB = bufA + (size_t)NN * DIM;
    ushort* Wlb  = bufB + (size_t)NN * DIM;         // 12*128*128
    ushort* Wrb  = Wlb + (size_t)NL * DIM * DIM;
    ushort* W1b  = Wrb + (size_t)NL * DIM * DIM;    // 128*128

    const int* src = ei;
    const int* dst = ei + NE;

    // converts
    cvt_kernel<<<(NN * DIM / 8 + 255) / 256, 256, 0, stream>>>(x, xb, NN * DIM / 8);
    cvt_kernel<<<(NL * DIM * DIM / 8 + 255) / 256, 256, 0, stream>>>(Wl, Wlb, NL * DIM * DIM / 8);
    cvt_kernel<<<(NL * DIM * DIM / 8 + 255) / 256, 256, 0, stream>>>(Wr, Wrb, NL * DIM * DIM / 8);
    cvt_kernel<<<(DIM * DIM / 8 + 255) / 256, 256, 0, stream>>>(W1, W1b, DIM * DIM / 8);

    // CSR build
    const int NB = (NN + 1023) / 1024;   // 49
    hipMemsetAsync(counts, 0, NN * sizeof(int), stream);
    count_kernel<<<(NE + 255) / 256, 256, 0, stream>>>(dst, counts);
    scan1_kernel<<<NB, 1024, 0, stream>>>(counts, offsets, bsums);
    scan2_kernel<<<1, 64, 0, stream>>>(bsums, bbase, NB);
    scan3_kernel<<<(NN + 1 + 255) / 256, 256, 0, stream>>>(offsets, bbase);
    hipMemsetAsync(counts, 0, NN * sizeof(int), stream);
    fill_kernel<<<(NE + 255) / 256, 256, 0, stream>>>(src, dst, offsets, counts, csr);

    static const int AGGRS[NL] = {0, 1, 2, 0, 1, 2, 0, 1, 2, 0, 2, 1};
    const ushort* h = xb;
    dim3 agrd((NN * 64 + 255) / 256);
    dim3 ggrd((NN + 127) / 128);
    for (int i = 0; i < NL; ++i) {
        ushort* aggbuf = (i & 1) ? bufB : bufA;
        if (AGGRS[i] == 0)
            aggregate_kernel<0><<<agrd, 256, 0, stream>>>(h, aggbuf, csr, offsets);
        else if (AGGRS[i] == 1)
            aggregate_kernel<1><<<agrd, 256, 0, stream>>>(h, aggbuf, csr, offsets);
        else
            aggregate_kernel<2><<<agrd, 256, 0, stream>>>(h, aggbuf, csr, offsets);
        gemm_kernel<<<ggrd, 256, 0, stream>>>(aggbuf, Wlb + (size_t)i * DIM * DIM, h,
                                              Wrb + (size_t)i * DIM * DIM,
                                              bl + (size_t)i * DIM, aggbuf, 2);
        h = aggbuf;
    }
    // final: relu(h@W1^T + b1) -> other buffer, then 128->2 projection
    ushort* h2 = (h == bufA) ? bufB : bufA;
    gemm_kernel<<<ggrd, 256, 0, stream>>>(h, W1b, nullptr, nullptr, b1, h2, 1);
    out_kernel<<<agrd, 256, 0, stream>>>(h2, W2, b2, out);
}